// Round 5
// baseline (181.246 us; speedup 1.0000x reference)
//
#include <hip/hip_runtime.h>
#include <hip/hip_bf16.h>

#define BATCH   16384
#define NSTEPS  100
#define DT_     0.01f
#define SQRTDT  0.1f
#define SIGMA0_ 0.5f

typedef _Float16  f16x2  __attribute__((ext_vector_type(2)));
typedef _Float16  f16x4  __attribute__((ext_vector_type(4)));
typedef _Float16  f16x8  __attribute__((ext_vector_type(8)));
typedef __fp16    h16x2  __attribute__((ext_vector_type(2)));
typedef float     f32x4  __attribute__((ext_vector_type(4)));

typedef const __attribute__((address_space(1))) void* gas_ptr;
typedef __attribute__((address_space(3))) void*       las_ptr;

__global__ void zero_out_kernel(float* out) { if (threadIdx.x == 0) out[0] = 0.0f; }

static __device__ __forceinline__ f16x4 pk4(const f32x4& d) {
    union { h16x2 h[2]; f16x4 v; } c;
    c.h[0] = __builtin_amdgcn_cvt_pkrtz(d[0], d[1]);
    c.h[1] = __builtin_amdgcn_cvt_pkrtz(d[2], d[3]);
    return c.v;
}

// R5: 8 paths/wave -> 2048 fully independent waves = 2 waves/SIMD with ZERO
// inter-wave sync (unlike R2's barrier-lockstep split). R4 showed the loop
// is latency-bound at 1 wave/SIMD (removing VALU ops left duration flat;
// effective ~4.4cy/VALU, ~16cy/MFMA = dependent latency). Two co-resident
// waves hide each other's latencies; per-wave instruction stream unchanged.
// Layout: B-frag path column = ln15, so lanes 8-15 duplicate paths 0-7
// (clean duplicates via ln15&7 noise reads); reduction masks ln15<8.
// Keeps R4's t-table (A1*t+C1 hoisted to LDS, prefetched ping-pong),
// L3 bias-in-C, SQRTDT folding.
__launch_bounds__(256, 2)
__global__ void deepbsde_kernel(
    const float* __restrict__ y0,  const float* __restrict__ Y0,
    const float* __restrict__ zW1, const float* __restrict__ zb1,
    const float* __restrict__ zW2, const float* __restrict__ zb2,
    const float* __restrict__ zW3, const float* __restrict__ zb3,
    const float* __restrict__ qW1, const float* __restrict__ qb1,
    const float* __restrict__ qW2, const float* __restrict__ qb2,
    const float* __restrict__ qW3, const float* __restrict__ qb3,
    const float* __restrict__ dW,  const float* __restrict__ dZ,
    float* __restrict__ out)
{
    __shared__ __align__(16) char ring[4][8][192];        // [wave][slot][8 paths * 24B]
    __shared__ __align__(16) _Float16 tbl[NSTEPS * 128];  // [step][q4][16 f16x2]

    const int tid  = threadIdx.x;
    const int lane = tid & 63;
    const int w    = tid >> 6;
    const int ln15 = lane & 15, q4 = lane >> 4;
    const int p3   = (ln15 & 7) * 3;      // path-in-wave noise offset
    const int gw   = (blockIdx.x << 2) + w;
    const int pbase = gw << 3;            // 8 paths per wave

    auto fill = [&](int i) {
        if (lane < 12) {
            const char* g = (lane < 6)
                ? (const char*)dW + ((size_t)i * BATCH + pbase) * 12 + (size_t)lane * 16
                : (const char*)dZ + ((size_t)i * BATCH + pbase) * 12 + (size_t)(lane - 6) * 16;
            __builtin_amdgcn_global_load_lds((gas_ptr)g, (las_ptr)&ring[w][i & 7][0],
                                             16, 0, 0);
        }
    };
    fill(0); fill(1); fill(2); fill(3);   // start HBM traffic before prologue math

    // ---- one-time t-table: entry (i,q4e,mlp,m) = A1[m]*t_i + C1[m] (pk f16),
    //      t_i accumulated exactly as the original loop did. ----
    {
        float tt = 0.0f;
        for (int i = 0; i < NSTEPS; ++i) {
            int r = (tid - (i << 6)) & 255;
            if (r < 64) {
                int q4e = r >> 4, mlp = (r >> 3) & 1, m = r & 7;
                const float* Wp = mlp ? qW1 : zW1;
                const float* bp = mlp ? qb1 : zb1;
                int i0 = 2*m, i1 = 2*m + 1;
                int k0 = 32*(i0 >> 3) + 8*q4e + (i0 & 7);
                int k1 = 32*(i1 >> 3) + 8*q4e + (i1 & 7);
                _Float16 th = (_Float16)tt;
                f16x2 A = {(_Float16)Wp[k0], (_Float16)Wp[k1]};
                f16x2 C = {(_Float16)bp[k0], (_Float16)bp[k1]};
                f16x2 tv = {th, th};
                f16x2 v = A*tv + C;                     // v_pk_fma_f16, as before
                int idx = (i*4 + q4e)*16 + mlp*8 + m;
                *(f16x2*)&tbl[idx << 1] = v;
            }
            tt += DT_;
        }
    }

    // ---- layer-1 y-coefficients (B1 = W1 row 1) as f16x2 pairs ----
    f16x2 B1z[8], B1q[8];
#pragma unroll
    for (int m = 0; m < 8; ++m) {
        int i0 = 2*m, i1 = 2*m + 1;
        int k0 = 32*(i0 >> 3) + 8*q4 + (i0 & 7);
        int k1 = 32*(i1 >> 3) + 8*q4 + (i1 & 7);
        B1z[m] = (f16x2){(_Float16)zW1[64 + k0], (_Float16)zW1[64 + k1]};
        B1q[m] = (f16x2){(_Float16)qW1[64 + k0], (_Float16)qW1[64 + k1]};
    }

    // ---- resident W2^T A-frags in f16: A[n=16tN+ln15][k=32f+8q4+j] ----
    f16x8 AfZ[4][2], AfQ[4][2];
#pragma unroll
    for (int tN = 0; tN < 4; ++tN)
#pragma unroll
        for (int f = 0; f < 2; ++f)
#pragma unroll
            for (int j = 0; j < 8; ++j) {
                int k = 32*f + 8*q4 + j, n = 16*tN + ln15;
                AfZ[tN][f][j] = (_Float16)zW2[k*64 + n];
                AfQ[tN][f][j] = (_Float16)qW2[k*64 + n];
            }

    // ---- layer-2 bias along Dt rows: row n = 16tN + 4q4 + r ----
    f32x4 b2zv[4], b2qv[4];
#pragma unroll
    for (int tN = 0; tN < 4; ++tN)
#pragma unroll
        for (int r = 0; r < 4; ++r) {
            b2zv[tN][r] = zb2[16*tN + 4*q4 + r];
            b2qv[tN][r] = qb2[16*tN + 4*q4 + r];
        }

    // ---- layer-3 combined A-frags for 16x16x32 (z prescaled by SQRTDT) ----
    const int c3 = ln15 & 3;
    f16x8 A3[4];
#pragma unroll
    for (int f = 0; f < 4; ++f)
#pragma unroll
        for (int j = 0; j < 8; ++j) {
            int tN = 2*(f & 1) + (j >> 2);
            int n  = 16*tN + 4*q4 + (j & 3);
            float wv = (f < 2) ? ((c3 < 3)  ? SQRTDT * zW3[n*3 + c3] : 0.0f)
                               : ((c3 == 3) ? qW3[n]                 : 0.0f);
            A3[f][j] = (_Float16)wv;
        }

    float y = y0[0], Yv = Y0[0], acc = 0.0f;
    const float CSIG = SIGMA0_ * SQRTDT;       // diffusion coefficient
    const float NHDT = -0.5f * DT_;            // -f*dt factor
    const f32x4 C3bias = {SQRTDT * zb3[0], SQRTDT * zb3[1], SQRTDT * zb3[2], qb3[0]};

    const f16x2 zero2h = {(_Float16)0.0f, (_Float16)0.0f};
    const f16x4 zero4h = {(_Float16)0.0f, (_Float16)0.0f, (_Float16)0.0f, (_Float16)0.0f};
    const f32x4 zero4  = {0.0f, 0.0f, 0.0f, 0.0f};

    // cur/nxt ping-pong registers for the t-table (4 x f16x8 each)
    f16x8 cz0, cz1, cq0, cq1, dz0, dz1, dq0, dq1;

    auto body = [&](int i,
                    f16x8& tz0, f16x8& tz1, f16x8& tq0, f16x8& tq1,
                    f16x8& uz0, f16x8& uz1, f16x8& uq0, f16x8& uq1) {
        const float* sl = (const float*)&ring[w][i & 7][0];
        float nw0 = sl[p3 + 0], nw1 = sl[p3 + 1], nw2 = sl[p3 + 2];
        float nz0 = sl[24 + p3 + 0], nz1 = sl[24 + p3 + 1], nz2 = sl[24 + p3 + 2];

        // prefetch next step's t-table slice (consumed next body call)
        int ip = i + 1; ip = (ip > NSTEPS - 1) ? NSTEPS - 1 : ip;
        {
            const f16x8* tp = (const f16x8*)(tbl + (ip*4 + q4)*32);
            uz0 = tp[0]; uz1 = tp[1]; uq0 = tp[2]; uq1 = tp[3];
        }

        // ---- h1: max(B1*y + T, 0) in packed f16; pairs ARE the B-frag ----
        _Float16 yh = (_Float16)y;
        const f16x2 yv = {yh, yh};
        union U8 { f16x8 v; f16x2 h[4]; };
        U8 Tz0; Tz0.v = tz0; U8 Tz1; Tz1.v = tz1;
        U8 Tq0; Tq0.v = tq0; U8 Tq1; Tq1.v = tq1;
        union { f16x2 h[4]; f16x8 v; } bz0, bz1, bq0, bq1;
#pragma unroll
        for (int m = 0; m < 4; ++m) {
            bz0.h[m] = __builtin_elementwise_max((f16x2)(B1z[m]*yv + Tz0.h[m]), zero2h);
            bq0.h[m] = __builtin_elementwise_max((f16x2)(B1q[m]*yv + Tq0.h[m]), zero2h);
            bz1.h[m] = __builtin_elementwise_max((f16x2)(B1z[m+4]*yv + Tz1.h[m]), zero2h);
            bq1.h[m] = __builtin_elementwise_max((f16x2)(B1q[m+4]*yv + Tq1.h[m]), zero2h);
        }

        // ---- layer-2: f16 MFMA, Dt[n][path]; pack then packed relu ----
        union { f16x4 q[4]; f16x8 o[2]; } Bz, Bq;
#pragma unroll
        for (int tN = 0; tN < 4; ++tN) {
            f32x4 dz = b2zv[tN];
            dz = __builtin_amdgcn_mfma_f32_16x16x32_f16(AfZ[tN][0], bz0.v, dz, 0, 0, 0);
            dz = __builtin_amdgcn_mfma_f32_16x16x32_f16(AfZ[tN][1], bz1.v, dz, 0, 0, 0);
            f32x4 dq = b2qv[tN];
            dq = __builtin_amdgcn_mfma_f32_16x16x32_f16(AfQ[tN][0], bq0.v, dq, 0, 0, 0);
            dq = __builtin_amdgcn_mfma_f32_16x16x32_f16(AfQ[tN][1], bq1.v, dq, 0, 0, 0);
            Bz.q[tN] = __builtin_elementwise_max(pk4(dz), zero4h);
            Bq.q[tN] = __builtin_elementwise_max(pk4(dq), zero4h);
        }

        // ---- layer-3: biases ride the z-chain C-input; P = (z0s,z1s,z2s,q) ----
        f32x4 Pz = C3bias, Pq = zero4;
        Pz = __builtin_amdgcn_mfma_f32_16x16x32_f16(A3[0], Bz.o[0], Pz, 0, 0, 0);
        Pz = __builtin_amdgcn_mfma_f32_16x16x32_f16(A3[1], Bz.o[1], Pz, 0, 0, 0);
        Pq = __builtin_amdgcn_mfma_f32_16x16x32_f16(A3[2], Bq.o[0], Pq, 0, 0, 0);
        Pq = __builtin_amdgcn_mfma_f32_16x16x32_f16(A3[3], Bq.o[1], Pq, 0, 0, 0);
        f32x4 P = Pz + Pq;

        // ---- scalar epilogue (z pre-scaled by SQRTDT, biases already in P) ----
        float zs0 = P[0], zs1 = P[1], zs2 = P[2], qv = P[3];
        float zdw = fmaf(zs2, nw2, fmaf(zs1, nw1, zs0*nw0));
        float zdz = fmaf(zs2, nz2, fmaf(zs1, nz1, zs0*nz0));
        float snw = (nw0 + nw1) + nw2;
        Yv = fmaf(NHDT*qv, qv, Yv) + zdw;
        float r = zdw - zdz;                       // residual: (Y - f*DT) cancels
        acc = fmaf(r, r, acc);
        y = fmaf(CSIG, snw, fmaf(qv, DT_, y));
    };

    __syncthreads();                               // table visible to all waves
    {   // step-0 table slice
        const f16x8* tp0 = (const f16x8*)(tbl + q4*32);
        cz0 = tp0[0]; cz1 = tp0[1]; cq0 = tp0[2]; cq1 = tp0[3];
    }

#pragma unroll 1
    for (int i = 0; i < NSTEPS - 4; i += 2) {
        __builtin_amdgcn_s_waitcnt(0x0F73);   // vmcnt(3): slot i complete
        fill(i + 4);
        body(i,     cz0, cz1, cq0, cq1, dz0, dz1, dq0, dq1);
        __builtin_amdgcn_s_waitcnt(0x0F73);   // vmcnt(3): slot i+1 complete
        fill(i + 5);
        body(i + 1, dz0, dz1, dq0, dq1, cz0, cz1, cq0, cq1);
    }
    __builtin_amdgcn_s_waitcnt(0x0F70);       // vmcnt(0): drain remaining fills
    body(NSTEPS - 4, cz0, cz1, cq0, cq1, dz0, dz1, dq0, dq1);
    body(NSTEPS - 3, dz0, dz1, dq0, dq1, cz0, cz1, cq0, cq1);
    body(NSTEPS - 2, cz0, cz1, cq0, cq1, dz0, dz1, dq0, dq1);
    body(NSTEPS - 1, dz0, dz1, dq0, dq1, cz0, cz1, cq0, cq1);

    float dterm = Yv - y*y;
    acc = fmaf(dterm, dterm, acc);

    // valid data: q4==0 row-quad AND the 8 real paths (ln15<8); lanes 8-15
    // are duplicates of paths 0-7 and must not be double-counted
    float val = (q4 == 0 && ln15 < 8) ? acc : 0.0f;
#pragma unroll
    for (int off = 1; off < 64; off <<= 1) val += __shfl_xor(val, off);
    if (lane == 0) atomicAdd(out, val * (1.0f / BATCH));
}

extern "C" void kernel_launch(void* const* d_in, const int* in_sizes, int n_in,
                              void* d_out, int out_size, void* d_ws, size_t ws_size,
                              hipStream_t stream)
{
    zero_out_kernel<<<1, 64, 0, stream>>>((float*)d_out);
    deepbsde_kernel<<<512, 256, 0, stream>>>(
        (const float*)d_in[0],  (const float*)d_in[1],
        (const float*)d_in[2],  (const float*)d_in[3],
        (const float*)d_in[4],  (const float*)d_in[5],
        (const float*)d_in[6],  (const float*)d_in[7],
        (const float*)d_in[8],  (const float*)d_in[9],
        (const float*)d_in[10], (const float*)d_in[11],
        (const float*)d_in[12], (const float*)d_in[13],
        (const float*)d_in[14], (const float*)d_in[15],
        (float*)d_out);
}

// Round 6
// 165.153 us; speedup vs baseline: 1.0974x; 1.0974x over previous
//
#include <hip/hip_runtime.h>
#include <hip/hip_bf16.h>

#define BATCH   16384
#define NSTEPS  100
#define DT_     0.01f
#define SQRTDT  0.1f
#define SIGMA0_ 0.5f

typedef _Float16  f16x2  __attribute__((ext_vector_type(2)));
typedef _Float16  f16x4  __attribute__((ext_vector_type(4)));
typedef _Float16  f16x8  __attribute__((ext_vector_type(8)));
typedef __fp16    h16x2  __attribute__((ext_vector_type(2)));
typedef float     f32x4  __attribute__((ext_vector_type(4)));

typedef const __attribute__((address_space(1))) void* gas_ptr;
typedef __attribute__((address_space(3))) void*       las_ptr;

__global__ void zero_out_kernel(float* out) { if (threadIdx.x == 0) out[0] = 0.0f; }

static __device__ __forceinline__ f16x4 pk4(const f32x4& d) {
    union { h16x2 h[2]; f16x4 v; } c;
    c.h[0] = __builtin_amdgcn_cvt_pkrtz(d[0], d[1]);
    c.h[1] = __builtin_amdgcn_cvt_pkrtz(d[2], d[3]);
    return c.v;
}

// R6: pipelined z/q wave-pair split with NO barriers (fixes both R2's
// lockstep and R5's 2x duplication). Insight: the per-step q->z exchange is
// unnecessary -- r = z.dw - z.dz has no q, and Yv is only needed terminally:
// Yv_N = Y0 + SUM(-0.5 q^2 dt) + SUM(z.dw). q-wave owns the y-recurrence and
// accumulates Facc; z-wave accumulates Ysum + residual acc. Only coupling:
// q publishes y(i+1) to an 8-deep LDS ring with a monotonic flag; z consumes
// y(i) one full step later (constant pipeline lag, not a per-step cost).
// Back-pressure: z publishes progress; q polls it only when >=6 ahead.
// Each wave runs ~half of R4's body -> 2048 waves (2/SIMD, R5-proven
// overlap) at ~1.05x total work. Keeps R4's t-table, bias-in-C, SQRTDT fold.
__launch_bounds__(256, 2)
__global__ void deepbsde_kernel(
    const float* __restrict__ y0,  const float* __restrict__ Y0,
    const float* __restrict__ zW1, const float* __restrict__ zb1,
    const float* __restrict__ zW2, const float* __restrict__ zb2,
    const float* __restrict__ zW3, const float* __restrict__ zb3,
    const float* __restrict__ qW1, const float* __restrict__ qb1,
    const float* __restrict__ qW2, const float* __restrict__ qb2,
    const float* __restrict__ qW3, const float* __restrict__ qb3,
    const float* __restrict__ dW,  const float* __restrict__ dZ,
    float* __restrict__ out)
{
    __shared__ __align__(16) char zring[2][8][384];       // [group][slot][16p * 24B]
    __shared__ __align__(16) char qring[2][8][192];       // [group][slot][16p * 12B] dW only
    __shared__ __align__(16) _Float16 tbl[NSTEPS * 128];  // [step][q4][16 f16x2]
    __shared__ float yring[2][8][16];                     // y(step) ring, slot = step&7
    __shared__ float ffin[2][16];                         // q-wave Facc finals
    __shared__ int   flags[2][2];                         // [g][0]=qflag, [g][1]=zprog

    const int tid  = threadIdx.x;
    const int lane = tid & 63;
    const int w    = tid >> 6;        // 0..3
    const int g    = w & 1;           // path group
    const bool isQ = (w >= 2);
    const int ln15 = lane & 15, q4 = lane >> 4;
    const int gw   = (blockIdx.x << 1) + g;
    const int pbase = gw << 4;        // 16 paths per group

    if (tid < 4) ((int*)flags)[tid] = 0;

    auto fillz = [&](int i) {
        if (lane < 24) {
            const char* gp = (lane < 12)
                ? (const char*)dW + ((size_t)i * BATCH + pbase) * 12 + (size_t)lane * 16
                : (const char*)dZ + ((size_t)i * BATCH + pbase) * 12 + (size_t)(lane - 12) * 16;
            __builtin_amdgcn_global_load_lds((gas_ptr)gp, (las_ptr)&zring[g][i & 7][0],
                                             16, 0, 0);
        }
    };
    auto fillq = [&](int i) {
        if (lane < 12) {
            const char* gp = (const char*)dW + ((size_t)i * BATCH + pbase) * 12 + (size_t)lane * 16;
            __builtin_amdgcn_global_load_lds((gas_ptr)gp, (las_ptr)&qring[g][i & 7][0],
                                             16, 0, 0);
        }
    };
    if (!isQ) { fillz(0); fillz(1); fillz(2); fillz(3); }
    else      { fillq(0); fillq(1); fillq(2); fillq(3); }

    // ---- one-time t-table (both MLP halves), identical arithmetic to R4 ----
    {
        float tt = 0.0f;
        for (int i = 0; i < NSTEPS; ++i) {
            int r = (tid - (i << 6)) & 255;
            if (r < 64) {
                int q4e = r >> 4, mlp = (r >> 3) & 1, m = r & 7;
                const float* Wp = mlp ? qW1 : zW1;
                const float* bp = mlp ? qb1 : zb1;
                int i0 = 2*m, i1 = 2*m + 1;
                int k0 = 32*(i0 >> 3) + 8*q4e + (i0 & 7);
                int k1 = 32*(i1 >> 3) + 8*q4e + (i1 & 7);
                _Float16 th = (_Float16)tt;
                f16x2 A = {(_Float16)Wp[k0], (_Float16)Wp[k1]};
                f16x2 C = {(_Float16)bp[k0], (_Float16)bp[k1]};
                f16x2 tv = {th, th};
                f16x2 v = A*tv + C;
                int idx = (i*4 + q4e)*16 + mlp*8 + m;
                *(f16x2*)&tbl[idx << 1] = v;
            }
            tt += DT_;
        }
    }

    // ---- role-selected weights (each wave loads only its MLP) ----
    const float* W1p = isQ ? qW1 : zW1;
    const float* W2p = isQ ? qW2 : zW2;
    const float* b2p = isQ ? qb2 : zb2;

    f16x2 B1[8];
#pragma unroll
    for (int m = 0; m < 8; ++m) {
        int i0 = 2*m, i1 = 2*m + 1;
        int k0 = 32*(i0 >> 3) + 8*q4 + (i0 & 7);
        int k1 = 32*(i1 >> 3) + 8*q4 + (i1 & 7);
        B1[m] = (f16x2){(_Float16)W1p[64 + k0], (_Float16)W1p[64 + k1]};
    }

    f16x8 Af[4][2];
#pragma unroll
    for (int tN = 0; tN < 4; ++tN)
#pragma unroll
        for (int f = 0; f < 2; ++f)
#pragma unroll
            for (int j = 0; j < 8; ++j) {
                int k = 32*f + 8*q4 + j, n = 16*tN + ln15;
                Af[tN][f][j] = (_Float16)W2p[k*64 + n];
            }

    f32x4 b2v[4];
#pragma unroll
    for (int tN = 0; tN < 4; ++tN)
#pragma unroll
        for (int r = 0; r < 4; ++r)
            b2v[tN][r] = b2p[16*tN + 4*q4 + r];

    const int c3 = ln15 & 3;
    f16x8 A3[2];
#pragma unroll
    for (int fl = 0; fl < 2; ++fl)
#pragma unroll
        for (int j = 0; j < 8; ++j) {
            int tN = 2*fl + (j >> 2);
            int n  = 16*tN + 4*q4 + (j & 3);
            float wv = isQ ? ((c3 == 3) ? qW3[n]                 : 0.0f)
                           : ((c3 < 3)  ? SQRTDT * zW3[n*3 + c3] : 0.0f);
            A3[fl][j] = (_Float16)wv;
        }

    const f32x4 C3b = isQ ? (f32x4){0.0f, 0.0f, 0.0f, qb3[0]}
                          : (f32x4){SQRTDT*zb3[0], SQRTDT*zb3[1], SQRTDT*zb3[2], 0.0f};

    const float CSIG = SIGMA0_ * SQRTDT;
    const float NHDT = -0.5f * DT_;
    const float y0v = y0[0], Y0v = Y0[0];

    const f16x2 zero2h = {(_Float16)0.0f, (_Float16)0.0f};
    const f16x4 zero4h = {(_Float16)0.0f, (_Float16)0.0f, (_Float16)0.0f, (_Float16)0.0f};

    // ---- role-agnostic single-MLP step: (y, t-slice) -> P ----
    auto mlp = [&](float ycur, f16x8 t0, f16x8 t1) -> f32x4 {
        _Float16 yh = (_Float16)ycur;
        const f16x2 yv = {yh, yh};
        union U8 { f16x8 v; f16x2 h[4]; };
        U8 T0; T0.v = t0; U8 T1; T1.v = t1;
        union { f16x2 h[4]; f16x8 v; } b0, b1;
#pragma unroll
        for (int m = 0; m < 4; ++m) {
            b0.h[m] = __builtin_elementwise_max((f16x2)(B1[m]*yv   + T0.h[m]), zero2h);
            b1.h[m] = __builtin_elementwise_max((f16x2)(B1[m+4]*yv + T1.h[m]), zero2h);
        }
        union { f16x4 q[4]; f16x8 o[2]; } Bh;
#pragma unroll
        for (int tN = 0; tN < 4; ++tN) {
            f32x4 d = b2v[tN];
            d = __builtin_amdgcn_mfma_f32_16x16x32_f16(Af[tN][0], b0.v, d, 0, 0, 0);
            d = __builtin_amdgcn_mfma_f32_16x16x32_f16(Af[tN][1], b1.v, d, 0, 0, 0);
            Bh.q[tN] = __builtin_elementwise_max(pk4(d), zero4h);
        }
        f32x4 Pv = C3b;
        Pv = __builtin_amdgcn_mfma_f32_16x16x32_f16(A3[0], Bh.o[0], Pv, 0, 0, 0);
        Pv = __builtin_amdgcn_mfma_f32_16x16x32_f16(A3[1], Bh.o[1], Pv, 0, 0, 0);
        return Pv;
    };

    __syncthreads();   // table + flag init visible; ONLY block-wide sync

    f16x8 c0, c1, d0, d1;

    if (!isQ) {
        // ================= z-wave: consumes y with 1-step lag =================
        float y = y0v, Ysum = 0.0f, acc = 0.0f;
        { const f16x8* tp = (const f16x8*)(tbl + q4*32); c0 = tp[0]; c1 = tp[1]; }

        auto zbody = [&](int i, f16x8& t0, f16x8& t1, f16x8& u0, f16x8& u1) {
            const float* sl = (const float*)&zring[g][i & 7][0];
            float nw0 = sl[ln15*3 + 0], nw1 = sl[ln15*3 + 1], nw2 = sl[ln15*3 + 2];
            float nz0 = sl[48 + ln15*3 + 0], nz1 = sl[48 + ln15*3 + 1], nz2 = sl[48 + ln15*3 + 2];
            int ip = i + 1; ip = (ip > NSTEPS - 1) ? NSTEPS - 1 : ip;
            { const f16x8* tp = (const f16x8*)(tbl + (ip*4 + q4)*32); u0 = tp[0]; u1 = tp[1]; }

            f32x4 P = mlp(y, t0, t1);
            float zs0 = P[0], zs1 = P[1], zs2 = P[2];
            float zdw = fmaf(zs2, nw2, fmaf(zs1, nw1, zs0*nw0));
            float zdz = fmaf(zs2, nz2, fmaf(zs1, nz1, zs0*nz0));
            Ysum += zdw;
            float r = zdw - zdz;
            acc = fmaf(r, r, acc);

            // fetch y(i+1): published by q-wave at end of its step i
            volatile int* qf = &flags[g][0];
            while (*qf < i + 1) { }
            y = *(volatile float*)&yring[g][(i + 1) & 7][ln15];
            if (lane == 0) *(volatile int*)&flags[g][1] = i + 1;   // consumed y(i+1)
        };

#pragma unroll 1
        for (int i = 0; i < NSTEPS - 4; i += 2) {
            __builtin_amdgcn_s_waitcnt(0x0F73);   // vmcnt(3)
            fillz(i + 4);
            zbody(i,     c0, c1, d0, d1);
            __builtin_amdgcn_s_waitcnt(0x0F73);
            fillz(i + 5);
            zbody(i + 1, d0, d1, c0, c1);
        }
        __builtin_amdgcn_s_waitcnt(0x0F70);       // vmcnt(0)
        zbody(NSTEPS - 4, c0, c1, d0, d1);
        zbody(NSTEPS - 3, d0, d1, c0, c1);
        zbody(NSTEPS - 2, c0, c1, d0, d1);
        zbody(NSTEPS - 1, d0, d1, c0, c1);

        // terminal: wait for q finals
        {
            volatile int* qf = &flags[g][0];
            while (*qf < NSTEPS + 1) { }
        }
        float Fq  = *(volatile float*)&ffin[g][ln15];
        float Yvf = Y0v + Fq + Ysum;               // Y0 + SUM(-.5 q^2 dt) + SUM(z.dw)
        float dterm = Yvf - y*y;                   // y = y(NSTEPS) from the ring
        acc = fmaf(dterm, dterm, acc);

        float val = (q4 == 0) ? acc : 0.0f;
#pragma unroll
        for (int off = 1; off < 64; off <<= 1) val += __shfl_xor(val, off);
        if (lane == 0) atomicAdd(out, val * (1.0f / BATCH));
    } else {
        // ================= q-wave: owns y-recurrence, publishes y =================
        float y = y0v, Facc = 0.0f;
        { const f16x8* tp = (const f16x8*)(tbl + q4*32); c0 = tp[2]; c1 = tp[3]; }

        auto qbody = [&](int j, f16x8& t0, f16x8& t1, f16x8& u0, f16x8& u1) {
            const float* sl = (const float*)&qring[g][j & 7][0];
            float nw0 = sl[ln15*3 + 0], nw1 = sl[ln15*3 + 1], nw2 = sl[ln15*3 + 2];

            f32x4 P = mlp(y, t0, t1);
            float qv = P[3];

            // back-pressure: never run >6 steps ahead of z's consumption
            if (j >= 6) {
                volatile int* zp = &flags[g][1];
                while (*zp < j - 5) { }
            }

            float snw = (nw0 + nw1) + nw2;
            Facc = fmaf(NHDT*qv, qv, Facc);
            y = fmaf(CSIG, snw, fmaf(qv, DT_, y));

            if (q4 == 0) *(volatile float*)&yring[g][(j + 1) & 7][ln15] = y;
            __builtin_amdgcn_s_waitcnt(0xC07F);    // lgkmcnt(0): y committed
            if (lane == 0) *(volatile int*)&flags[g][0] = j + 1;

            int jp = j + 1; jp = (jp > NSTEPS - 1) ? NSTEPS - 1 : jp;
            { const f16x8* tp = (const f16x8*)(tbl + (jp*4 + q4)*32); u0 = tp[2]; u1 = tp[3]; }
        };

#pragma unroll 1
        for (int j = 0; j < NSTEPS - 4; j += 2) {
            __builtin_amdgcn_s_waitcnt(0x0F73);   // vmcnt(3)
            fillq(j + 4);
            qbody(j,     c0, c1, d0, d1);
            __builtin_amdgcn_s_waitcnt(0x0F73);
            fillq(j + 5);
            qbody(j + 1, d0, d1, c0, c1);
        }
        __builtin_amdgcn_s_waitcnt(0x0F70);       // vmcnt(0)
        qbody(NSTEPS - 4, c0, c1, d0, d1);
        qbody(NSTEPS - 3, d0, d1, c0, c1);
        qbody(NSTEPS - 2, c0, c1, d0, d1);
        qbody(NSTEPS - 1, d0, d1, c0, c1);

        if (q4 == 0) *(volatile float*)&ffin[g][ln15] = Facc;
        __builtin_amdgcn_s_waitcnt(0xC07F);        // lgkmcnt(0)
        if (lane == 0) *(volatile int*)&flags[g][0] = NSTEPS + 1;
    }
}

extern "C" void kernel_launch(void* const* d_in, const int* in_sizes, int n_in,
                              void* d_out, int out_size, void* d_ws, size_t ws_size,
                              hipStream_t stream)
{
    zero_out_kernel<<<1, 64, 0, stream>>>((float*)d_out);
    deepbsde_kernel<<<512, 256, 0, stream>>>(
        (const float*)d_in[0],  (const float*)d_in[1],
        (const float*)d_in[2],  (const float*)d_in[3],
        (const float*)d_in[4],  (const float*)d_in[5],
        (const float*)d_in[6],  (const float*)d_in[7],
        (const float*)d_in[8],  (const float*)d_in[9],
        (const float*)d_in[10], (const float*)d_in[11],
        (const float*)d_in[12], (const float*)d_in[13],
        (const float*)d_in[14], (const float*)d_in[15],
        (float*)d_out);
}

// Round 7
// 155.204 us; speedup vs baseline: 1.1678x; 1.0641x over previous
//
#include <hip/hip_runtime.h>
#include <hip/hip_bf16.h>

#define BATCH   16384
#define NSTEPS  100
#define DT_     0.01f
#define SQRTDT  0.1f
#define SIGMA0_ 0.5f

typedef _Float16  f16x2  __attribute__((ext_vector_type(2)));
typedef _Float16  f16x4  __attribute__((ext_vector_type(4)));
typedef _Float16  f16x8  __attribute__((ext_vector_type(8)));
typedef __fp16    h16x2  __attribute__((ext_vector_type(2)));
typedef float     f32x4  __attribute__((ext_vector_type(4)));

typedef const __attribute__((address_space(1))) void* gas_ptr;
typedef __attribute__((address_space(3))) void*       las_ptr;

__global__ void zero_out_kernel(float* out) { if (threadIdx.x == 0) out[0] = 0.0f; }

static __device__ __forceinline__ f16x4 pk4(const f32x4& d) {
    union { h16x2 h[2]; f16x4 v; } c;
    c.h[0] = __builtin_amdgcn_cvt_pkrtz(d[0], d[1]);
    c.h[1] = __builtin_amdgcn_cvt_pkrtz(d[2], d[3]);
    return c.v;
}

// R7: decoupled producer-consumer (fixes R6's hidden lockstep).
//  - y-ring is FULL DEPTH (101 entries): no wraparound -> q-wave's
//    back-pressure poll deleted; q runs unboundedly ahead of z.
//  - q publishes y(j+1) with a bare ds_write each step; ONE lgkmcnt(0) +
//    flag raise per 4 steps (amortized ~30cy/step vs R6's ~300).
//  - z consumes y in batches of 4 with ONE flag poll per batch; q is far
//    ahead in steady state so the poll succeeds on first read.
//  - Yv decomposed terminally: Yv_N = Y0 + SUM(-.5 q^2 dt) [q-wave Facc]
//    + SUM(z.dw) [z-wave Ysum]; residual r = z.dw - z.dz needs no q.
// Keeps R4's t-table, bias-in-C, SQRTDT fold; R6's role-split weights.
__launch_bounds__(256, 2)
__global__ void deepbsde_kernel(
    const float* __restrict__ y0,  const float* __restrict__ Y0,
    const float* __restrict__ zW1, const float* __restrict__ zb1,
    const float* __restrict__ zW2, const float* __restrict__ zb2,
    const float* __restrict__ zW3, const float* __restrict__ zb3,
    const float* __restrict__ qW1, const float* __restrict__ qb1,
    const float* __restrict__ qW2, const float* __restrict__ qb2,
    const float* __restrict__ qW3, const float* __restrict__ qb3,
    const float* __restrict__ dW,  const float* __restrict__ dZ,
    float* __restrict__ out)
{
    __shared__ __align__(16) char zring[2][8][384];       // [group][slot][16p * 24B]
    __shared__ __align__(16) char qring[2][8][192];       // [group][slot][16p * 12B] dW only
    __shared__ __align__(16) _Float16 tbl[NSTEPS * 128];  // [step][q4][16 f16x2]
    __shared__ float yring[2][NSTEPS + 1][16];            // full-depth y history
    __shared__ float ffin[2][16];                         // q-wave Facc finals
    __shared__ int   flags[2][2];                         // [g][0]=q progress flag

    const int tid  = threadIdx.x;
    const int lane = tid & 63;
    const int w    = tid >> 6;        // 0..3
    const int g    = w & 1;           // path group
    const bool isQ = (w >= 2);
    const int ln15 = lane & 15, q4 = lane >> 4;
    const int gw   = (blockIdx.x << 1) + g;
    const int pbase = gw << 4;        // 16 paths per group

    if (tid < 4) ((int*)flags)[tid] = 0;

    auto fillz = [&](int i) {
        if (lane < 24) {
            const char* gp = (lane < 12)
                ? (const char*)dW + ((size_t)i * BATCH + pbase) * 12 + (size_t)lane * 16
                : (const char*)dZ + ((size_t)i * BATCH + pbase) * 12 + (size_t)(lane - 12) * 16;
            __builtin_amdgcn_global_load_lds((gas_ptr)gp, (las_ptr)&zring[g][i & 7][0],
                                             16, 0, 0);
        }
    };
    auto fillq = [&](int i) {
        if (lane < 12) {
            const char* gp = (const char*)dW + ((size_t)i * BATCH + pbase) * 12 + (size_t)lane * 16;
            __builtin_amdgcn_global_load_lds((gas_ptr)gp, (las_ptr)&qring[g][i & 7][0],
                                             16, 0, 0);
        }
    };
    if (!isQ) { fillz(0); fillz(1); fillz(2); fillz(3); }
    else      { fillq(0); fillq(1); fillq(2); fillq(3); }

    // ---- one-time t-table (both MLP halves), identical arithmetic to R4 ----
    {
        float tt = 0.0f;
        for (int i = 0; i < NSTEPS; ++i) {
            int r = (tid - (i << 6)) & 255;
            if (r < 64) {
                int q4e = r >> 4, mlp_ = (r >> 3) & 1, m = r & 7;
                const float* Wp = mlp_ ? qW1 : zW1;
                const float* bp = mlp_ ? qb1 : zb1;
                int i0 = 2*m, i1 = 2*m + 1;
                int k0 = 32*(i0 >> 3) + 8*q4e + (i0 & 7);
                int k1 = 32*(i1 >> 3) + 8*q4e + (i1 & 7);
                _Float16 th = (_Float16)tt;
                f16x2 A = {(_Float16)Wp[k0], (_Float16)Wp[k1]};
                f16x2 C = {(_Float16)bp[k0], (_Float16)bp[k1]};
                f16x2 tv = {th, th};
                f16x2 v = A*tv + C;
                int idx = (i*4 + q4e)*16 + mlp_*8 + m;
                *(f16x2*)&tbl[idx << 1] = v;
            }
            tt += DT_;
        }
    }

    // ---- role-selected weights (each wave loads only its MLP) ----
    const float* W1p = isQ ? qW1 : zW1;
    const float* W2p = isQ ? qW2 : zW2;
    const float* b2p = isQ ? qb2 : zb2;

    f16x2 B1[8];
#pragma unroll
    for (int m = 0; m < 8; ++m) {
        int i0 = 2*m, i1 = 2*m + 1;
        int k0 = 32*(i0 >> 3) + 8*q4 + (i0 & 7);
        int k1 = 32*(i1 >> 3) + 8*q4 + (i1 & 7);
        B1[m] = (f16x2){(_Float16)W1p[64 + k0], (_Float16)W1p[64 + k1]};
    }

    f16x8 Af[4][2];
#pragma unroll
    for (int tN = 0; tN < 4; ++tN)
#pragma unroll
        for (int f = 0; f < 2; ++f)
#pragma unroll
            for (int j = 0; j < 8; ++j) {
                int k = 32*f + 8*q4 + j, n = 16*tN + ln15;
                Af[tN][f][j] = (_Float16)W2p[k*64 + n];
            }

    f32x4 b2v[4];
#pragma unroll
    for (int tN = 0; tN < 4; ++tN)
#pragma unroll
        for (int r = 0; r < 4; ++r)
            b2v[tN][r] = b2p[16*tN + 4*q4 + r];

    const int c3 = ln15 & 3;
    f16x8 A3[2];
#pragma unroll
    for (int fl = 0; fl < 2; ++fl)
#pragma unroll
        for (int j = 0; j < 8; ++j) {
            int tN = 2*fl + (j >> 2);
            int n  = 16*tN + 4*q4 + (j & 3);
            float wv = isQ ? ((c3 == 3) ? qW3[n]                 : 0.0f)
                           : ((c3 < 3)  ? SQRTDT * zW3[n*3 + c3] : 0.0f);
            A3[fl][j] = (_Float16)wv;
        }

    const f32x4 C3b = isQ ? (f32x4){0.0f, 0.0f, 0.0f, qb3[0]}
                          : (f32x4){SQRTDT*zb3[0], SQRTDT*zb3[1], SQRTDT*zb3[2], 0.0f};

    const float CSIG = SIGMA0_ * SQRTDT;
    const float NHDT = -0.5f * DT_;
    const float y0v = y0[0], Y0v = Y0[0];

    const f16x2 zero2h = {(_Float16)0.0f, (_Float16)0.0f};
    const f16x4 zero4h = {(_Float16)0.0f, (_Float16)0.0f, (_Float16)0.0f, (_Float16)0.0f};

    // ---- role-agnostic single-MLP step: (y, t-slice) -> P ----
    auto mlp = [&](float ycur, f16x8 t0, f16x8 t1) -> f32x4 {
        _Float16 yh = (_Float16)ycur;
        const f16x2 yv = {yh, yh};
        union U8 { f16x8 v; f16x2 h[4]; };
        U8 T0; T0.v = t0; U8 T1; T1.v = t1;
        union { f16x2 h[4]; f16x8 v; } b0, b1;
#pragma unroll
        for (int m = 0; m < 4; ++m) {
            b0.h[m] = __builtin_elementwise_max((f16x2)(B1[m]*yv   + T0.h[m]), zero2h);
            b1.h[m] = __builtin_elementwise_max((f16x2)(B1[m+4]*yv + T1.h[m]), zero2h);
        }
        union { f16x4 q[4]; f16x8 o[2]; } Bh;
#pragma unroll
        for (int tN = 0; tN < 4; ++tN) {
            f32x4 d = b2v[tN];
            d = __builtin_amdgcn_mfma_f32_16x16x32_f16(Af[tN][0], b0.v, d, 0, 0, 0);
            d = __builtin_amdgcn_mfma_f32_16x16x32_f16(Af[tN][1], b1.v, d, 0, 0, 0);
            Bh.q[tN] = __builtin_elementwise_max(pk4(d), zero4h);
        }
        f32x4 Pv = C3b;
        Pv = __builtin_amdgcn_mfma_f32_16x16x32_f16(A3[0], Bh.o[0], Pv, 0, 0, 0);
        Pv = __builtin_amdgcn_mfma_f32_16x16x32_f16(A3[1], Bh.o[1], Pv, 0, 0, 0);
        return Pv;
    };

    __syncthreads();   // table + flag init visible; ONLY block-wide sync

    f16x8 c0, c1, d0, d1;

    if (!isQ) {
        // ========== z-wave: batched y consumption, no per-step sync ==========
        float Ysum = 0.0f, acc = 0.0f;
        float ya, yb, yc, yd;
        { const f16x8* tp = (const f16x8*)(tbl + q4*32); c0 = tp[0]; c1 = tp[1]; }

        auto zbody = [&](int i, float ycur, f16x8& t0, f16x8& t1, f16x8& u0, f16x8& u1) {
            const float* sl = (const float*)&zring[g][i & 7][0];
            float nw0 = sl[ln15*3 + 0], nw1 = sl[ln15*3 + 1], nw2 = sl[ln15*3 + 2];
            float nz0 = sl[48 + ln15*3 + 0], nz1 = sl[48 + ln15*3 + 1], nz2 = sl[48 + ln15*3 + 2];
            int ip = i + 1; ip = (ip > NSTEPS - 1) ? NSTEPS - 1 : ip;
            { const f16x8* tp = (const f16x8*)(tbl + (ip*4 + q4)*32); u0 = tp[0]; u1 = tp[1]; }

            f32x4 P = mlp(ycur, t0, t1);
            float zs0 = P[0], zs1 = P[1], zs2 = P[2];
            float zdw = fmaf(zs2, nw2, fmaf(zs1, nw1, zs0*nw0));
            float zdz = fmaf(zs2, nz2, fmaf(zs1, nz1, zs0*nz0));
            Ysum += zdw;
            float r = zdw - zdz;
            acc = fmaf(r, r, acc);
        };
        auto ybatch = [&](int base) {  // needs flag >= base+4; reads y(base+1..base+4)
            volatile int* qf = &flags[g][0];
            while (*qf < base + 4) { }
            ya = *(volatile float*)&yring[g][base + 1][ln15];
            yb = *(volatile float*)&yring[g][base + 2][ln15];
            yc = *(volatile float*)&yring[g][base + 3][ln15];
            yd = *(volatile float*)&yring[g][base + 4][ln15];
        };

        __builtin_amdgcn_s_waitcnt(0x0F73); fillz(4);
        zbody(0, y0v, c0, c1, d0, d1);
        ybatch(0);
#pragma unroll 1
        for (int b = 0; b < 23; ++b) {
            int i = 4*b;
            __builtin_amdgcn_s_waitcnt(0x0F73); fillz(i + 5);
            zbody(i + 1, ya, d0, d1, c0, c1);
            __builtin_amdgcn_s_waitcnt(0x0F73); fillz(i + 6);
            zbody(i + 2, yb, c0, c1, d0, d1);
            __builtin_amdgcn_s_waitcnt(0x0F73); fillz(i + 7);
            zbody(i + 3, yc, d0, d1, c0, c1);
            __builtin_amdgcn_s_waitcnt(0x0F73); fillz(i + 8);
            zbody(i + 4, yd, c0, c1, d0, d1);
            ybatch(i + 4);
        }
        // bodies 93..96 (fills 97..99 then none)
        __builtin_amdgcn_s_waitcnt(0x0F73); fillz(97);
        zbody(93, ya, d0, d1, c0, c1);
        __builtin_amdgcn_s_waitcnt(0x0F73); fillz(98);
        zbody(94, yb, c0, c1, d0, d1);
        __builtin_amdgcn_s_waitcnt(0x0F73); fillz(99);
        zbody(95, yc, d0, d1, c0, c1);
        __builtin_amdgcn_s_waitcnt(0x0F73);
        zbody(96, yd, c0, c1, d0, d1);
        ybatch(96);                        // y97..y100 (flag reaches 100)
        __builtin_amdgcn_s_waitcnt(0x0F72);
        zbody(97, ya, d0, d1, c0, c1);
        __builtin_amdgcn_s_waitcnt(0x0F71);
        zbody(98, yb, c0, c1, d0, d1);
        __builtin_amdgcn_s_waitcnt(0x0F70);
        zbody(99, yc, d0, d1, c0, c1);

        // terminal: wait for q finals (flag = NSTEPS+1)
        {
            volatile int* qf = &flags[g][0];
            while (*qf < NSTEPS + 1) { }
        }
        float Fq  = *(volatile float*)&ffin[g][ln15];
        float Yvf = Y0v + Fq + Ysum;       // Y0 + SUM(-.5 q^2 dt) + SUM(z.dw)
        float yT  = yd;                    // y(NSTEPS)
        float dterm = Yvf - yT*yT;
        acc = fmaf(dterm, dterm, acc);

        float val = (q4 == 0) ? acc : 0.0f;
#pragma unroll
        for (int off = 1; off < 64; off <<= 1) val += __shfl_xor(val, off);
        if (lane == 0) atomicAdd(out, val * (1.0f / BATCH));
    } else {
        // ========== q-wave: owns y-recurrence; publish-only, no polls ==========
        float y = y0v, Facc = 0.0f;
        { const f16x8* tp = (const f16x8*)(tbl + q4*32); c0 = tp[2]; c1 = tp[3]; }

        auto qbody = [&](int j, f16x8& t0, f16x8& t1, f16x8& u0, f16x8& u1) {
            const float* sl = (const float*)&qring[g][j & 7][0];
            float nw0 = sl[ln15*3 + 0], nw1 = sl[ln15*3 + 1], nw2 = sl[ln15*3 + 2];
            int jp = j + 1; jp = (jp > NSTEPS - 1) ? NSTEPS - 1 : jp;
            { const f16x8* tp = (const f16x8*)(tbl + (jp*4 + q4)*32); u0 = tp[2]; u1 = tp[3]; }

            f32x4 P = mlp(y, t0, t1);
            float qv = P[3];
            float snw = (nw0 + nw1) + nw2;
            Facc = fmaf(NHDT*qv, qv, Facc);
            y = fmaf(CSIG, snw, fmaf(qv, DT_, y));
            if (q4 == 0) *(volatile float*)&yring[g][j + 1][ln15] = y;  // bare ds_write
        };

#pragma unroll 1
        for (int jb = 0; jb < 24; ++jb) {
            int j = 4*jb;
            __builtin_amdgcn_s_waitcnt(0x0F73); fillq(j + 4);
            qbody(j,     c0, c1, d0, d1);
            __builtin_amdgcn_s_waitcnt(0x0F73); fillq(j + 5);
            qbody(j + 1, d0, d1, c0, c1);
            __builtin_amdgcn_s_waitcnt(0x0F73); fillq(j + 6);
            qbody(j + 2, c0, c1, d0, d1);
            __builtin_amdgcn_s_waitcnt(0x0F73); fillq(j + 7);
            qbody(j + 3, d0, d1, c0, c1);
            __builtin_amdgcn_s_waitcnt(0xC07F);                 // lgkmcnt(0): y writes landed
            if (lane == 0) *(volatile int*)&flags[g][0] = j + 4;
        }
        // tail 96..99 (no fills; declining vmcnt)
        __builtin_amdgcn_s_waitcnt(0x0F73);
        qbody(96, c0, c1, d0, d1);
        __builtin_amdgcn_s_waitcnt(0x0F72);
        qbody(97, d0, d1, c0, c1);
        __builtin_amdgcn_s_waitcnt(0x0F71);
        qbody(98, c0, c1, d0, d1);
        __builtin_amdgcn_s_waitcnt(0x0F70);
        qbody(99, d0, d1, c0, c1);
        __builtin_amdgcn_s_waitcnt(0xC07F);                     // y(100) landed
        if (lane == 0) *(volatile int*)&flags[g][0] = NSTEPS;

        if (q4 == 0) *(volatile float*)&ffin[g][ln15] = Facc;
        __builtin_amdgcn_s_waitcnt(0xC07F);
        if (lane == 0) *(volatile int*)&flags[g][0] = NSTEPS + 1;
    }
}

extern "C" void kernel_launch(void* const* d_in, const int* in_sizes, int n_in,
                              void* d_out, int out_size, void* d_ws, size_t ws_size,
                              hipStream_t stream)
{
    zero_out_kernel<<<1, 64, 0, stream>>>((float*)d_out);
    deepbsde_kernel<<<512, 256, 0, stream>>>(
        (const float*)d_in[0],  (const float*)d_in[1],
        (const float*)d_in[2],  (const float*)d_in[3],
        (const float*)d_in[4],  (const float*)d_in[5],
        (const float*)d_in[6],  (const float*)d_in[7],
        (const float*)d_in[8],  (const float*)d_in[9],
        (const float*)d_in[10], (const float*)d_in[11],
        (const float*)d_in[12], (const float*)d_in[13],
        (const float*)d_in[14], (const float*)d_in[15],
        (float*)d_out);
}